// Round 4
// baseline (879.796 us; speedup 1.0000x reference)
//
#include <hip/hip_runtime.h>

typedef _Float16 hf;
typedef _Float16 hf8 __attribute__((ext_vector_type(8)));
typedef float f32x4 __attribute__((ext_vector_type(4)));

static constexpr int BATCH = 4;
static constexpr int TPTS  = 65536;
static constexpr int NPTS  = BATCH * TPTS;   // 262144
static constexpr int R3    = 32768;
static constexpr int NVOX  = BATCH * R3;     // 131072

// fragment-linear f16 weight buffers (units of hf) inside d_out scratch.
static constexpr int OFF_WPOS = 0;         // K=64(pad 60), N=256: 2048 chunks
static constexpr int OFF_W0   = 16384;     // 5 x (K=256,N=128)
static constexpr int OFF_W1   = 180224;    // 5 x (K=128,N=128)
static constexpr int OFF_WSC  = 262144;    // 5 x (K=256,N=128)
static constexpr int OFF_WC   = 425984;    // K=128,N=128
static constexpr int NCHUNKS  = 55296;

__device__ constexpr int kpat(int g, int j) { return (j & 3) + 4 * g + 16 * (j >> 2); }

#define MFMA16(a, b, c) __builtin_amdgcn_mfma_f32_16x16x32_f16((a), (b), (c), 0, 0, 0)

__device__ inline hf8 relu8(hf8 a) {
#pragma unroll
  for (int i = 0; i < 8; ++i) a[i] = (a[i] > (hf)0) ? a[i] : (hf)0;
  return a;
}
__device__ inline f32x4 splat4(float v) {
  f32x4 r; r[0] = v; r[1] = v; r[2] = v; r[3] = v; return r;
}
__device__ inline hf8 ldfrag(const hf* __restrict__ base, int kc, int nt, int NT, int lane) {
  return *(const hf8*)(base + (((size_t)(kc * NT + nt) * 64 + lane) << 3));
}

// ---------------- weight fragment prep --------------------------------------
__global__ __launch_bounds__(256) void k_prep(
    const float* __restrict__ wpos, const float* __restrict__ w0,
    const float* __restrict__ w1,  const float* __restrict__ wsc,
    const float* __restrict__ wc,  hf* __restrict__ fr)
{
  const int cid = blockIdx.x * 256 + threadIdx.x;
  if (cid >= NCHUNKS) return;
  const float* src; hf* dst; int NT, N, kmax, loc;
  if (cid < 2048) {
    src = wpos; dst = fr + OFF_WPOS; NT = 16; N = 256; kmax = 60; loc = cid;
  } else if (cid < 22528) {
    int l5 = cid - 2048; int i = l5 >> 12; loc = l5 & 4095;
    src = w0 + (size_t)i * 32768; dst = fr + OFF_W0 + (size_t)i * 32768;
    NT = 8; N = 128; kmax = 256;
  } else if (cid < 32768) {
    int l5 = cid - 22528; int i = l5 >> 11; loc = l5 & 2047;
    src = w1 + (size_t)i * 16384; dst = fr + OFF_W1 + (size_t)i * 16384;
    NT = 8; N = 128; kmax = 128;
  } else if (cid < 53248) {
    int l5 = cid - 32768; int i = l5 >> 12; loc = l5 & 4095;
    src = wsc + (size_t)i * 32768; dst = fr + OFF_WSC + (size_t)i * 32768;
    NT = 8; N = 128; kmax = 256;
  } else {
    loc = cid - 53248; src = wc; dst = fr + OFF_WC; NT = 8; N = 128; kmax = 128;
  }
  const int lane = loc & 63;
  const int rest = loc >> 6;
  const int nt = rest % NT, kc = rest / NT;
  const int g = lane >> 4;
  const int n = nt * 16 + (lane & 15);
  union { hf8 h; hf f[8]; } o;
#pragma unroll
  for (int j = 0; j < 8; ++j) {
    int k = kc * 32 + kpat(g, j);
    o.f[j] = (k < kmax) ? (hf)src[(size_t)k * N + n] : (hf)0;
  }
  *(hf8*)(dst + ((size_t)loc << 3)) = o.h;
}

// -------- pos-enc + fc_pos (60->256) via MFMA -------------------------------
__global__ __launch_bounds__(256) void k_pre(
    const float* __restrict__ p, const hf* __restrict__ fr,
    const float* __restrict__ bpos,
    hf* __restrict__ xlo, hf* __restrict__ xhi, int* __restrict__ idxbuf)
{
  const int wv = threadIdx.x >> 6, lane = threadIdx.x & 63;
  const int r = lane & 15, g = lane >> 4;
  const int t0 = blockIdx.x * 64;

  float px[4], py[4], pz[4];
#pragma unroll
  for (int mf = 0; mf < 4; ++mf) {
    const float* pp = p + (size_t)(t0 + mf * 16 + r) * 3;
    px[mf] = pp[0]; py[mf] = pp[1]; pz[mf] = pp[2];
  }
  if (wv == 0 && g == 0) {
#pragma unroll
    for (int mf = 0; mf < 4; ++mf) {
      float nx = fminf(fmaxf(px[mf] / 1.101f + 0.5f, 0.0f), 0.999f);
      float ny = fminf(fmaxf(py[mf] / 1.101f + 0.5f, 0.0f), 0.999f);
      float nz = fminf(fmaxf(pz[mf] / 1.101f + 0.5f, 0.0f), 0.999f);
      idxbuf[t0 + mf * 16 + r] =
          (int)(nx * 32.f) + 32 * (int)(ny * 32.f) + 1024 * (int)(nz * 32.f);
    }
  }

  f32x4 acc[4][4];
#pragma unroll
  for (int nf = 0; nf < 4; ++nf) {
    float bv = bpos[wv * 64 + nf * 16 + r];
#pragma unroll
    for (int mf = 0; mf < 4; ++mf) acc[mf][nf] = splat4(bv);
  }

#pragma unroll
  for (int kc = 0; kc < 2; ++kc) {
    hf8 a[4];
#pragma unroll
    for (int mf = 0; mf < 4; ++mf) {
      union { hf8 h; hf f[8]; } av;
#pragma unroll
      for (int j = 0; j < 8; ++j) {
        int k = kc * 32 + kpat(g, j);
        float val = 0.f;
        if (k < 60) {
          int fi = k / 6, rem = k - 6 * fi;
          int comp = (rem >= 3) ? rem - 3 : rem;
          float pc = (comp == 0) ? px[mf] : (comp == 1) ? py[mf] : pz[mf];
          float ang = (float)(1 << fi) * 3.14159274101257324f * pc;
          val = (rem < 3) ? __sinf(ang) : __cosf(ang);
        }
        av.f[j] = (hf)val;
      }
      a[mf] = av.h;
    }
#pragma unroll
    for (int nf = 0; nf < 4; ++nf) {
      hf8 b = ldfrag(fr + OFF_WPOS, kc, wv * 4 + nf, 16, lane);
#pragma unroll
      for (int mf = 0; mf < 4; ++mf) acc[mf][nf] = MFMA16(a[mf], b, acc[mf][nf]);
    }
  }

  hf* dst_base = (wv < 2) ? xlo : xhi;
  const int nbase = (wv & 1) * 64;
#pragma unroll
  for (int mf = 0; mf < 4; ++mf)
#pragma unroll
    for (int nf = 0; nf < 4; ++nf)
#pragma unroll
      for (int reg = 0; reg < 4; ++reg) {
        int m = mf * 16 + 4 * g + reg;
        int n = nbase + nf * 16 + r;
        dst_base[(size_t)(t0 + m) * 128 + n] = (hf)acc[mf][nf][reg];
      }
}

// ---------------- CSR build -------------------------------------------------
__global__ __launch_bounds__(256) void k_count(
    const int* __restrict__ idxbuf, int* __restrict__ cnt)
{
  const int t = blockIdx.x * 256 + threadIdx.x;
  const int bv = ((t >> 16) << 15) | idxbuf[t];
  atomicAdd(&cnt[bv], 1);
}

__global__ __launch_bounds__(256) void k_scan(
    const int* __restrict__ cnt, int* __restrict__ start, int* __restrict__ total)
{
  __shared__ int s[256];
  __shared__ int base_s;
  const int tid = threadIdx.x;
  const int v0 = blockIdx.x * 512;
  const int a = cnt[v0 + 2 * tid], b = cnt[v0 + 2 * tid + 1];
  const int sum = a + b;
  s[tid] = sum;
  __syncthreads();
  for (int off = 1; off < 256; off <<= 1) {
    int x = (tid >= off) ? s[tid - off] : 0;
    __syncthreads();
    s[tid] += x;
    __syncthreads();
  }
  if (tid == 255) base_s = atomicAdd(total, s[255]);
  __syncthreads();
  const int excl = base_s + s[tid] - sum;
  start[v0 + 2 * tid]     = excl;
  start[v0 + 2 * tid + 1] = excl + a;
}

// advances start[bv] to range END; pool/write recover begin = end - cnt
__global__ __launch_bounds__(256) void k_fill(
    const int* __restrict__ idxbuf, int* __restrict__ start, int* __restrict__ csr)
{
  const int t = blockIdx.x * 256 + threadIdx.x;
  const int bv = ((t >> 16) << 15) | idxbuf[t];
  const int pos = atomicAdd(&start[bv], 1);
  csr[pos] = t;
}

// ---------------- pool: gather-max per voxel (16 lanes / voxel) -------------
__global__ __launch_bounds__(256) void k_pool(
    const hf* __restrict__ net, const int* __restrict__ start,
    const int* __restrict__ cnt, const int* __restrict__ csr,
    hf* __restrict__ fea)
{
  const int gid = blockIdx.x * 256 + threadIdx.x;
  const int bv = gid >> 4;          // voxel id (b<<15)|v
  const int q = gid & 15;           // lane-in-group: channels 8q..8q+7
  const int n = cnt[bv];
  if (n == 0) return;
  const int end = start[bv], beg = end - n;
  float m[8];
#pragma unroll
  for (int e = 0; e < 8; ++e) m[e] = -1e30f;
  for (int i = beg; i < end; ++i) {
    const int t = csr[i];
    union { uint4 u; hf h[8]; } x;
    x.u = *(const uint4*)(net + (size_t)t * 128 + 8 * q);
#pragma unroll
    for (int e = 0; e < 8; ++e) m[e] = fmaxf(m[e], (float)x.h[e]);
  }
  union { uint4 u; hf h[8]; } o;
#pragma unroll
  for (int e = 0; e < 8; ++e) o.h[e] = (hf)m[e];
  *(uint4*)(fea + ((size_t)bv << 7) + 8 * q) = o.u;
}

// ---- ResnetBlockFC for 64 points via MFMA (32KB LDS, 4 blocks/CU). ---------
// ---- Pooled half of X: MODE0: xhi[t] ; MODE1: fea[(b<<15)|v] ---------------
template <int MODE>
__global__ __launch_bounds__(256, 4) void k_res_t(
    hf* __restrict__ net, const hf* __restrict__ feav,
    const int* __restrict__ idxbuf,
    const hf* __restrict__ w0f, const hf* __restrict__ w1f,
    const hf* __restrict__ wscf,
    const float* __restrict__ b0, const float* __restrict__ b1)
{
  __shared__ __align__(16) hf swX[16384];   // 32 KB: X frags; H (16KB) aliases
  const int tid = threadIdx.x;
  const int wv = tid >> 6, lane = tid & 63;
  const int r = lane & 15, g = lane >> 4;
  const int wm = wv >> 1, wn = wv & 1;
  const int t0 = blockIdx.x * 64;

  // gather X (K=256: net ch 0-127, pooled ch 128-255) into frag-linear LDS
  for (int cc = tid; cc < 2048; cc += 256) {
    const int cl = cc & 63;
    const int kc = (cc >> 6) & 7;
    const int mt = cc >> 9;            // 0..3
    const int rr = cl & 15, gg = cl >> 4;
    const int t = t0 + mt * 16 + rr;
    const int c1 = kc * 32 + 4 * gg;
    union { hf8 h; uint2 u2[2]; } x;
    const hf* srcp;
    if (kc < 4) {
      srcp = net + (size_t)t * 128 + c1;
    } else if (MODE == 0) {
      srcp = feav + (size_t)t * 128 + (c1 - 128);
    } else {
      const int b = t >> 16;
      const int v = idxbuf[t];
      srcp = feav + (((size_t)((b << 15) | v)) << 7) + (c1 - 128);
    }
    x.u2[0] = *(const uint2*)(srcp);
    x.u2[1] = *(const uint2*)(srcp + 16);
    *(hf8*)(swX + ((size_t)cc << 3)) = x.h;
  }
  __syncthreads();

  // fc0: relu(X)@w0+b0  and  shortcut: X@wsc  (share A-fragments)
  f32x4 h[2][4], d[2][4];
#pragma unroll
  for (int nf = 0; nf < 4; ++nf) {
    const int n = wn * 64 + nf * 16 + r;
    const float bh = b0[n], bd = b1[n];
#pragma unroll
    for (int mf = 0; mf < 2; ++mf) { h[mf][nf] = splat4(bh); d[mf][nf] = splat4(bd); }
  }
#pragma unroll 2
  for (int kc = 0; kc < 8; ++kc) {
    hf8 a[2], ar[2];
#pragma unroll
    for (int mf = 0; mf < 2; ++mf) {
      a[mf] = *(const hf8*)(swX + (((size_t)((wm * 2 + mf) * 8 + kc) * 64 + lane) << 3));
      ar[mf] = relu8(a[mf]);
    }
#pragma unroll
    for (int nf = 0; nf < 4; ++nf) {
      hf8 bw0 = ldfrag(w0f, kc, wn * 4 + nf, 8, lane);
      hf8 bws = ldfrag(wscf, kc, wn * 4 + nf, 8, lane);
#pragma unroll
      for (int mf = 0; mf < 2; ++mf) {
        h[mf][nf] = MFMA16(ar[mf], bw0, h[mf][nf]);
        d[mf][nf] = MFMA16(a[mf],  bws, d[mf][nf]);
      }
    }
  }
  __syncthreads();

  // H = relu(h) -> frag-linear LDS (64 pts x K=128, 16KB, aliases X region).
  // Bank swizzle: slot = gg*16 + ((rr + gg) & 15). slot%8 then covers all 8
  // residues across a wave's b16 stores -> 16 banks, 2-way (free, m136);
  // multiplier-4 variant cancels mod 32 and is NOT used.
#pragma unroll
  for (int mf = 0; mf < 2; ++mf)
#pragma unroll
    for (int nf = 0; nf < 4; ++nf)
#pragma unroll
      for (int reg = 0; reg < 4; ++reg) {
        int m = wm * 32 + mf * 16 + 4 * g + reg;
        int k = wn * 64 + nf * 16 + r;
        float hv = fmaxf(h[mf][nf][reg], 0.f);
        int mt = m >> 4, rr = m & 15;
        int kc = k >> 5, kk = k & 31;
        int gg = (kk >> 2) & 3;
        int e = (kk & 3) + 4 * (kk >> 4);
        int slot = gg * 16 + ((rr + gg) & 15);
        swX[(((size_t)(mt * 4 + kc) * 64 + slot) << 3) + e] = (hf)hv;
      }
  __syncthreads();

  // fc1: H @ w1 (+b1 already in d) accumulated onto shortcut
  const int lidx = g * 16 + ((r + g) & 15);   // matches H swizzle
#pragma unroll
  for (int kc = 0; kc < 4; ++kc) {
    hf8 a[2];
#pragma unroll
    for (int mf = 0; mf < 2; ++mf)
      a[mf] = *(const hf8*)(swX + (((size_t)((wm * 2 + mf) * 4 + kc) * 64 + lidx) << 3));
#pragma unroll
    for (int nf = 0; nf < 4; ++nf) {
      hf8 bw1 = ldfrag(w1f, kc, wn * 4 + nf, 8, lane);
#pragma unroll
      for (int mf = 0; mf < 2; ++mf) d[mf][nf] = MFMA16(a[mf], bw1, d[mf][nf]);
    }
  }

#pragma unroll
  for (int mf = 0; mf < 2; ++mf)
#pragma unroll
    for (int nf = 0; nf < 4; ++nf)
#pragma unroll
      for (int reg = 0; reg < 4; ++reg) {
        int m = wm * 32 + mf * 16 + 4 * g + reg;
        int n = wn * 64 + nf * 16 + r;
        net[(size_t)(t0 + m) * 128 + n] = (hf)d[mf][nf][reg];
      }
}

// ---------------- fc_c via MFMA, in-place over net (64-pt blocks) -----------
__global__ __launch_bounds__(256, 4) void k_fcc(
    hf* __restrict__ net, const hf* __restrict__ wcf, const float* __restrict__ bc)
{
  __shared__ __align__(16) hf swX[8192];   // 16 KB
  const int tid = threadIdx.x;
  const int wv = tid >> 6, lane = tid & 63;
  const int r = lane & 15, g = lane >> 4;
  const int wm = wv >> 1, wn = wv & 1;
  const int t0 = blockIdx.x * 64;

  for (int cc = tid; cc < 1024; cc += 256) {
    const int cl = cc & 63;
    const int kc = (cc >> 6) & 3;
    const int mt = cc >> 8;   // 0..3
    const int rr = cl & 15, gg = cl >> 4;
    const int t = t0 + mt * 16 + rr;
    const int c1 = kc * 32 + 4 * gg;
    union { hf8 h; uint2 u2[2]; } x;
    const hf* srcp = net + (size_t)t * 128 + c1;
    x.u2[0] = *(const uint2*)(srcp);
    x.u2[1] = *(const uint2*)(srcp + 16);
    *(hf8*)(swX + ((size_t)cc << 3)) = x.h;
  }
  __syncthreads();

  f32x4 d[2][4];
#pragma unroll
  for (int nf = 0; nf < 4; ++nf) {
    float bv = bc[wn * 64 + nf * 16 + r];
#pragma unroll
    for (int mf = 0; mf < 2; ++mf) d[mf][nf] = splat4(bv);
  }
#pragma unroll
  for (int kc = 0; kc < 4; ++kc) {
    hf8 a[2];
#pragma unroll
    for (int mf = 0; mf < 2; ++mf)
      a[mf] = *(const hf8*)(swX + (((size_t)((wm * 2 + mf) * 4 + kc) * 64 + lane) << 3));
#pragma unroll
    for (int nf = 0; nf < 4; ++nf) {
      hf8 b = ldfrag(wcf, kc, wn * 4 + nf, 8, lane);
#pragma unroll
      for (int mf = 0; mf < 2; ++mf) d[mf][nf] = MFMA16(a[mf], b, d[mf][nf]);
    }
  }

#pragma unroll
  for (int mf = 0; mf < 2; ++mf)
#pragma unroll
    for (int nf = 0; nf < 4; ++nf)
#pragma unroll
      for (int reg = 0; reg < 4; ++reg) {
        int m = wm * 32 + mf * 16 + 4 * g + reg;
        int n = wn * 64 + nf * 16 + r;
        net[(size_t)(t0 + m) * 128 + n] = (hf)d[mf][nf][reg];
      }
}

// ---------------- gather-mean + transpose -----------------------------------
__global__ __launch_bounds__(256) void k_write(
    const hf* __restrict__ cbuf, const int* __restrict__ start,
    const int* __restrict__ cnt, const int* __restrict__ csr,
    float* __restrict__ out)
{
  __shared__ float tile[128 * 65];
  const int tid = threadIdx.x;
  const int grp = tid >> 4, q = tid & 15;
  const int g0 = blockIdx.x * 64;        // voxel base, (b<<15)|v0
  for (int vl = grp; vl < 64; vl += 16) {
    const int bv = g0 + vl;
    const int n = cnt[bv];
    const int end = start[bv], beg = end - n;
    float s[8] = {0, 0, 0, 0, 0, 0, 0, 0};
    for (int i = beg; i < end; ++i) {
      const int t = csr[i];
      union { uint4 u; hf h[8]; } x;
      x.u = *(const uint4*)(cbuf + (size_t)t * 128 + 8 * q);
#pragma unroll
      for (int e = 0; e < 8; ++e) s[e] += (float)x.h[e];
    }
    const float inv = 1.0f / fmaxf((float)n, 1.0f);
#pragma unroll
    for (int e = 0; e < 8; ++e) tile[(8 * q + e) * 65 + vl] = s[e] * inv;
  }
  __syncthreads();
  const int b = g0 >> 15, v0 = g0 & 32767;
  for (int i = tid; i < 8192; i += 256) {
    const int c = i >> 6, vl = i & 63;
    out[(((size_t)(b * 128 + c)) << 15) + v0 + vl] = tile[c * 65 + vl];
  }
}

extern "C" void kernel_launch(void* const* d_in, const int* in_sizes, int n_in,
                              void* d_out, int out_size, void* d_ws, size_t ws_size,
                              hipStream_t stream)
{
  const float* p    = (const float*)d_in[0];
  const float* wpos = (const float*)d_in[1];
  const float* bpos = (const float*)d_in[2];
  const float* w0   = (const float*)d_in[3];
  const float* b0   = (const float*)d_in[4];
  const float* w1   = (const float*)d_in[5];
  const float* b1   = (const float*)d_in[6];
  const float* wsc  = (const float*)d_in[7];
  const float* wc   = (const float*)d_in[8];
  const float* bc   = (const float*)d_in[9];

  char* ws = (char*)d_ws;
  int* idxbuf = (int*)ws;                       // 1 MiB
  hf*  net    = (hf*)(ws + (1u << 20));         // 64 MiB
  char* A     = ws + (1u << 20) + (64u << 20);  // 64 MiB region:
  hf*  xhi    = (hf*)A;                         //   [0..64M)  alive k_pre -> k_res<0>
  hf*  fea    = (hf*)A;                         //   [0..32M)  alive pools (xhi dead)
  int* cnt32  = (int*)(A + (32u << 20));                 // 512 KiB
  int* total  = (int*)(A + (32u << 20) + 0x80000);       // 4 B
  int* startb = (int*)(A + (32u << 20) + 0x80400);       // 512 KiB
  int* csr    = (int*)(A + (32u << 20) + 0x100400);      // 1 MiB
  hf*  fr     = (hf*)d_out;  // weight frags; d_out fully overwritten by k_write

  k_prep<<<216, 256, 0, stream>>>(wpos, w0, w1, wsc, wc, fr);
  k_pre<<<NPTS / 64, 256, 0, stream>>>(p, fr, bpos, net, xhi, idxbuf);
  k_res_t<0><<<NPTS / 64, 256, 0, stream>>>(net, xhi, idxbuf,
      fr + OFF_W0, fr + OFF_W1, fr + OFF_WSC, b0, b1);

  // CSR build (xhi dead from here; cnt/start/csr live in its upper half)
  hipMemsetAsync(cnt32, 0, 0x80000 + 0x400, stream);  // cnt + total
  k_count<<<NPTS / 256, 256, 0, stream>>>(idxbuf, cnt32);
  k_scan<<<NVOX / 512, 256, 0, stream>>>(cnt32, startb, total);
  k_fill<<<NPTS / 256, 256, 0, stream>>>(idxbuf, startb, csr);

  for (int i = 1; i < 5; ++i) {
    k_pool<<<(NVOX * 16) / 256, 256, 0, stream>>>(net, startb, cnt32, csr, fea);
    k_res_t<1><<<NPTS / 64, 256, 0, stream>>>(net, fea, idxbuf,
        fr + OFF_W0 + (size_t)i * 32768, fr + OFF_W1 + (size_t)i * 16384,
        fr + OFF_WSC + (size_t)i * 32768, b0 + i * 128, b1 + i * 128);
  }

  k_fcc<<<NPTS / 64, 256, 0, stream>>>(net, fr + OFF_WC, bc);
  k_write<<<NVOX / 64, 256, 0, stream>>>(net, startb, cnt32, csr, (float*)d_out);
}

// Round 5
// 657.670 us; speedup vs baseline: 1.3377x; 1.3377x over previous
//
#include <hip/hip_runtime.h>

typedef _Float16 hf;
typedef _Float16 hf8 __attribute__((ext_vector_type(8)));
typedef float f32x4 __attribute__((ext_vector_type(4)));

static constexpr int BATCH = 4;
static constexpr int TPTS  = 65536;
static constexpr int NPTS  = BATCH * TPTS;   // 262144
static constexpr int R3    = 32768;
static constexpr int NVOX  = BATCH * R3;     // 131072

// fragment-linear f16 weight buffers (units of hf) inside d_out scratch.
static constexpr int OFF_WPOS = 0;         // K=64(pad 60), N=256: 2048 chunks
static constexpr int OFF_W0   = 16384;     // 5 x (K=256,N=128)
static constexpr int OFF_W1   = 180224;    // 5 x (K=128,N=128)
static constexpr int OFF_WSC  = 262144;    // 5 x (K=256,N=128)
static constexpr int OFF_WC   = 425984;    // K=128,N=128
static constexpr int NCHUNKS  = 55296;

__device__ constexpr int kpat(int g, int j) { return (j & 3) + 4 * g + 16 * (j >> 2); }

#define MFMA16(a, b, c) __builtin_amdgcn_mfma_f32_16x16x32_f16((a), (b), (c), 0, 0, 0)

__device__ inline hf8 relu8(hf8 a) {
#pragma unroll
  for (int i = 0; i < 8; ++i) a[i] = (a[i] > (hf)0) ? a[i] : (hf)0;
  return a;
}
__device__ inline f32x4 splat4(float v) {
  f32x4 r; r[0] = v; r[1] = v; r[2] = v; r[3] = v; return r;
}
__device__ inline hf8 ldfrag(const hf* __restrict__ base, int kc, int nt, int NT, int lane) {
  return *(const hf8*)(base + (((size_t)(kc * NT + nt) * 64 + lane) << 3));
}

// ---------------- weight fragment prep --------------------------------------
__global__ __launch_bounds__(256) void k_prep(
    const float* __restrict__ wpos, const float* __restrict__ w0,
    const float* __restrict__ w1,  const float* __restrict__ wsc,
    const float* __restrict__ wc,  hf* __restrict__ fr)
{
  const int cid = blockIdx.x * 256 + threadIdx.x;
  if (cid >= NCHUNKS) return;
  const float* src; hf* dst; int NT, N, kmax, loc;
  if (cid < 2048) {
    src = wpos; dst = fr + OFF_WPOS; NT = 16; N = 256; kmax = 60; loc = cid;
  } else if (cid < 22528) {
    int l5 = cid - 2048; int i = l5 >> 12; loc = l5 & 4095;
    src = w0 + (size_t)i * 32768; dst = fr + OFF_W0 + (size_t)i * 32768;
    NT = 8; N = 128; kmax = 256;
  } else if (cid < 32768) {
    int l5 = cid - 22528; int i = l5 >> 11; loc = l5 & 2047;
    src = w1 + (size_t)i * 16384; dst = fr + OFF_W1 + (size_t)i * 16384;
    NT = 8; N = 128; kmax = 128;
  } else if (cid < 53248) {
    int l5 = cid - 32768; int i = l5 >> 12; loc = l5 & 4095;
    src = wsc + (size_t)i * 32768; dst = fr + OFF_WSC + (size_t)i * 32768;
    NT = 8; N = 128; kmax = 256;
  } else {
    loc = cid - 53248; src = wc; dst = fr + OFF_WC; NT = 8; N = 128; kmax = 128;
  }
  const int lane = loc & 63;
  const int rest = loc >> 6;
  const int nt = rest % NT, kc = rest / NT;
  const int g = lane >> 4;
  const int n = nt * 16 + (lane & 15);
  union { hf8 h; hf f[8]; } o;
#pragma unroll
  for (int j = 0; j < 8; ++j) {
    int k = kc * 32 + kpat(g, j);
    o.f[j] = (k < kmax) ? (hf)src[(size_t)k * N + n] : (hf)0;
  }
  *(hf8*)(dst + ((size_t)loc << 3)) = o.h;
}

// ---------------- voxel index only ------------------------------------------
__global__ __launch_bounds__(256) void k_idx(
    const float* __restrict__ p, int* __restrict__ idxbuf)
{
  const int t = blockIdx.x * 256 + threadIdx.x;
  const float px = p[(size_t)t * 3 + 0];
  const float py = p[(size_t)t * 3 + 1];
  const float pz = p[(size_t)t * 3 + 2];
  float nx = fminf(fmaxf(px / 1.101f + 0.5f, 0.0f), 0.999f);
  float ny = fminf(fmaxf(py / 1.101f + 0.5f, 0.0f), 0.999f);
  float nz = fminf(fmaxf(pz / 1.101f + 0.5f, 0.0f), 0.999f);
  idxbuf[t] = (int)(nx * 32.f) + 32 * (int)(ny * 32.f) + 1024 * (int)(nz * 32.f);
}

// ---------------- CSR build -------------------------------------------------
__global__ __launch_bounds__(256) void k_count(
    const int* __restrict__ idxbuf, int* __restrict__ cnt)
{
  const int t = blockIdx.x * 256 + threadIdx.x;
  const int bv = ((t >> 16) << 15) | idxbuf[t];
  atomicAdd(&cnt[bv], 1);
}

__global__ __launch_bounds__(256) void k_scan(
    const int* __restrict__ cnt, int* __restrict__ start, int* __restrict__ total)
{
  __shared__ int s[256];
  __shared__ int base_s;
  const int tid = threadIdx.x;
  const int v0 = blockIdx.x * 512;
  const int a = cnt[v0 + 2 * tid], b = cnt[v0 + 2 * tid + 1];
  const int sum = a + b;
  s[tid] = sum;
  __syncthreads();
  for (int off = 1; off < 256; off <<= 1) {
    int x = (tid >= off) ? s[tid - off] : 0;
    __syncthreads();
    s[tid] += x;
    __syncthreads();
  }
  if (tid == 255) base_s = atomicAdd(total, s[255]);
  __syncthreads();
  const int excl = base_s + s[tid] - sum;
  start[v0 + 2 * tid]     = excl;
  start[v0 + 2 * tid + 1] = excl + a;
}

// fill: advance start[bv] to END; record sorted slot (spos, in-place over
// idxbuf) and voxel per sorted slot (svox).
__global__ __launch_bounds__(256) void k_fill(
    int* __restrict__ idxbuf, int* __restrict__ start, int* __restrict__ svox)
{
  const int t = blockIdx.x * 256 + threadIdx.x;
  const int bv = ((t >> 16) << 15) | idxbuf[t];
  const int pos = atomicAdd(&start[bv], 1);
  svox[pos] = bv;
  idxbuf[t] = pos;     // idxbuf becomes spos
}

// -------- fused: pos-enc + fc_pos (60->256) + ResnetBlock 0 (64 pts) --------
__global__ __launch_bounds__(256, 2) void k_fused0(
    const float* __restrict__ p, const hf* __restrict__ fr,
    const float* __restrict__ bpos,
    const hf* __restrict__ w0f, const hf* __restrict__ w1f,
    const hf* __restrict__ wscf,
    const float* __restrict__ b0, const float* __restrict__ b1,
    const int* __restrict__ spos, hf* __restrict__ net)
{
  __shared__ __align__(16) hf swX[16384];   // 32 KB: X frags; H (16KB) aliases
  __shared__ int sp[64];
  const int tid = threadIdx.x;
  const int wv = tid >> 6, lane = tid & 63;
  const int r = lane & 15, g = lane >> 4;
  const int t0 = blockIdx.x * 64;

  if (tid < 64) sp[tid] = spos[t0 + tid];

  float px[4], py[4], pz[4];
#pragma unroll
  for (int mf = 0; mf < 4; ++mf) {
    const float* pp = p + (size_t)(t0 + mf * 16 + r) * 3;
    px[mf] = pp[0]; py[mf] = pp[1]; pz[mf] = pp[2];
  }

  f32x4 acc[4][4];
#pragma unroll
  for (int nf = 0; nf < 4; ++nf) {
    float bv = bpos[wv * 64 + nf * 16 + r];
#pragma unroll
    for (int mf = 0; mf < 4; ++mf) acc[mf][nf] = splat4(bv);
  }
#pragma unroll
  for (int kc = 0; kc < 2; ++kc) {
    hf8 a[4];
#pragma unroll
    for (int mf = 0; mf < 4; ++mf) {
      union { hf8 h; hf f[8]; } av;
#pragma unroll
      for (int j = 0; j < 8; ++j) {
        int k = kc * 32 + kpat(g, j);
        float val = 0.f;
        if (k < 60) {
          int fi = k / 6, rem = k - 6 * fi;
          int comp = (rem >= 3) ? rem - 3 : rem;
          float pc = (comp == 0) ? px[mf] : (comp == 1) ? py[mf] : pz[mf];
          float ang = (float)(1 << fi) * 3.14159274101257324f * pc;
          val = (rem < 3) ? __sinf(ang) : __cosf(ang);
        }
        av.f[j] = (hf)val;
      }
      a[mf] = av.h;
    }
#pragma unroll
    for (int nf = 0; nf < 4; ++nf) {
      hf8 b = ldfrag(fr + OFF_WPOS, kc, wv * 4 + nf, 16, lane);
#pragma unroll
      for (int mf = 0; mf < 4; ++mf) acc[mf][nf] = MFMA16(a[mf], b, acc[mf][nf]);
    }
  }

  // X -> frag-linear LDS, swizzled slot
#pragma unroll
  for (int mf = 0; mf < 4; ++mf)
#pragma unroll
    for (int nf = 0; nf < 4; ++nf)
#pragma unroll
      for (int reg = 0; reg < 4; ++reg) {
        int rr = 4 * g + reg;
        int c  = wv * 64 + nf * 16 + r;
        int kc = c >> 5;
        int kk = c & 31;
        int gg = (kk >> 2) & 3;
        int e  = (kk & 3) + 4 * (kk >> 4);
        int slot = gg * 16 + ((rr + gg) & 15);
        swX[(((size_t)(mf * 8 + kc) * 64 + slot) << 3) + e] = (hf)acc[mf][nf][reg];
      }
  __syncthreads();

  const int wm = wv >> 1, wn = wv & 1;
  const int lidx = g * 16 + ((r + g) & 15);

  f32x4 h[2][4], d[2][4];
#pragma unroll
  for (int nf = 0; nf < 4; ++nf) {
    const int n = wn * 64 + nf * 16 + r;
    const float bh = b0[n], bd = b1[n];
#pragma unroll
    for (int mf = 0; mf < 2; ++mf) { h[mf][nf] = splat4(bh); d[mf][nf] = splat4(bd); }
  }
#pragma unroll 2
  for (int kc = 0; kc < 8; ++kc) {
    hf8 a[2], ar[2];
#pragma unroll
    for (int mf = 0; mf < 2; ++mf) {
      a[mf] = *(const hf8*)(swX + (((size_t)((wm * 2 + mf) * 8 + kc) * 64 + lidx) << 3));
      ar[mf] = relu8(a[mf]);
    }
#pragma unroll
    for (int nf = 0; nf < 4; ++nf) {
      hf8 bw0 = ldfrag(w0f, kc, wn * 4 + nf, 8, lane);
      hf8 bws = ldfrag(wscf, kc, wn * 4 + nf, 8, lane);
#pragma unroll
      for (int mf = 0; mf < 2; ++mf) {
        h[mf][nf] = MFMA16(ar[mf], bw0, h[mf][nf]);
        d[mf][nf] = MFMA16(a[mf],  bws, d[mf][nf]);
      }
    }
  }
  __syncthreads();

#pragma unroll
  for (int mf = 0; mf < 2; ++mf)
#pragma unroll
    for (int nf = 0; nf < 4; ++nf)
#pragma unroll
      for (int reg = 0; reg < 4; ++reg) {
        int m = wm * 32 + mf * 16 + 4 * g + reg;
        int k = wn * 64 + nf * 16 + r;
        float hv = fmaxf(h[mf][nf][reg], 0.f);
        int mt = m >> 4, rr = m & 15;
        int kc = k >> 5, kk = k & 31;
        int gg = (kk >> 2) & 3;
        int e = (kk & 3) + 4 * (kk >> 4);
        int slot = gg * 16 + ((rr + gg) & 15);
        swX[(((size_t)(mt * 4 + kc) * 64 + slot) << 3) + e] = (hf)hv;
      }
  __syncthreads();

#pragma unroll
  for (int kc = 0; kc < 4; ++kc) {
    hf8 a[2];
#pragma unroll
    for (int mf = 0; mf < 2; ++mf)
      a[mf] = *(const hf8*)(swX + (((size_t)((wm * 2 + mf) * 4 + kc) * 64 + lidx) << 3));
#pragma unroll
    for (int nf = 0; nf < 4; ++nf) {
      hf8 bw1 = ldfrag(w1f, kc, wn * 4 + nf, 8, lane);
#pragma unroll
      for (int mf = 0; mf < 2; ++mf) d[mf][nf] = MFMA16(a[mf], bw1, d[mf][nf]);
    }
  }

#pragma unroll
  for (int mf = 0; mf < 2; ++mf)
#pragma unroll
    for (int nf = 0; nf < 4; ++nf)
#pragma unroll
      for (int reg = 0; reg < 4; ++reg) {
        int m = wm * 32 + mf * 16 + 4 * g + reg;
        int n = wn * 64 + nf * 16 + r;
        net[(size_t)sp[m] * 128 + n] = (hf)d[mf][nf][reg];
      }
}

// ---------------- pool: streaming gather-max per voxel (16 lanes) -----------
__global__ __launch_bounds__(256) void k_pool(
    const hf* __restrict__ net, const int* __restrict__ start,
    const int* __restrict__ cnt, hf* __restrict__ fea)
{
  const int gid = blockIdx.x * 256 + threadIdx.x;
  const int bv = gid >> 4;
  const int q = gid & 15;
  const int n = cnt[bv];
  if (n == 0) return;
  const int end = start[bv], beg = end - n;
  float m[8];
#pragma unroll
  for (int e = 0; e < 8; ++e) m[e] = -1e30f;
  for (int i = beg; i < end; ++i) {
    union { uint4 u; hf h[8]; } x;
    x.u = *(const uint4*)(net + (size_t)i * 128 + 8 * q);
#pragma unroll
    for (int e = 0; e < 8; ++e) m[e] = fmaxf(m[e], (float)x.h[e]);
  }
  union { uint4 u; hf h[8]; } o;
#pragma unroll
  for (int e = 0; e < 8; ++e) o.h[e] = (hf)m[e];
  *(uint4*)(fea + ((size_t)bv << 7) + 8 * q) = o.u;
}

// ---- ResnetBlockFC for 128 sorted points via MFMA (64KB LDS) ---------------
__global__ __launch_bounds__(256, 2) void k_res(
    hf* __restrict__ net, const hf* __restrict__ fea,
    const int* __restrict__ svox,
    const hf* __restrict__ w0f, const hf* __restrict__ w1f,
    const hf* __restrict__ wscf,
    const float* __restrict__ b0, const float* __restrict__ b1)
{
  __shared__ __align__(16) hf swX[32768];   // 64 KB: X frags; H (32KB) aliases
  const int tid = threadIdx.x;
  const int wv = tid >> 6, lane = tid & 63;
  const int r = lane & 15, g = lane >> 4;
  const int wm = wv >> 1, wn = wv & 1;
  const int t0 = blockIdx.x * 128;
  const int lidx = g * 16 + ((r + g) & 15);

  for (int cc = tid; cc < 4096; cc += 256) {
    const int cl = cc & 63;
    const int kc = (cc >> 6) & 7;
    const int mt = cc >> 9;
    const int rr = cl & 15, gg = cl >> 4;
    const int t = t0 + mt * 16 + rr;
    const int c1 = kc * 32 + 4 * gg;
    union { hf8 h; uint2 u2[2]; } x;
    const hf* srcp;
    if (kc < 4) {
      srcp = net + (size_t)t * 128 + c1;
    } else {
      srcp = fea + (((size_t)svox[t]) << 7) + (c1 - 128);
    }
    x.u2[0] = *(const uint2*)(srcp);
    x.u2[1] = *(const uint2*)(srcp + 16);
    const int slot = gg * 16 + ((rr + gg) & 15);
    *(hf8*)(swX + (((size_t)((cc & ~63) + slot)) << 3)) = x.h;
  }
  __syncthreads();

  f32x4 h[4][4], d[4][4];
#pragma unroll
  for (int nf = 0; nf < 4; ++nf) {
    const int n = wn * 64 + nf * 16 + r;
    const float bh = b0[n], bd = b1[n];
#pragma unroll
    for (int mf = 0; mf < 4; ++mf) { h[mf][nf] = splat4(bh); d[mf][nf] = splat4(bd); }
  }
#pragma unroll 2
  for (int kc = 0; kc < 8; ++kc) {
    hf8 a[4], ar[4];
#pragma unroll
    for (int mf = 0; mf < 4; ++mf) {
      a[mf] = *(const hf8*)(swX + (((size_t)((wm * 4 + mf) * 8 + kc) * 64 + lidx) << 3));
      ar[mf] = relu8(a[mf]);
    }
#pragma unroll
    for (int nf = 0; nf < 4; ++nf) {
      hf8 bw0 = ldfrag(w0f, kc, wn * 4 + nf, 8, lane);
      hf8 bws = ldfrag(wscf, kc, wn * 4 + nf, 8, lane);
#pragma unroll
      for (int mf = 0; mf < 4; ++mf) {
        h[mf][nf] = MFMA16(ar[mf], bw0, h[mf][nf]);
        d[mf][nf] = MFMA16(a[mf],  bws, d[mf][nf]);
      }
    }
  }
  __syncthreads();

#pragma unroll
  for (int mf = 0; mf < 4; ++mf)
#pragma unroll
    for (int nf = 0; nf < 4; ++nf)
#pragma unroll
      for (int reg = 0; reg < 4; ++reg) {
        int m = wm * 64 + mf * 16 + 4 * g + reg;
        int k = wn * 64 + nf * 16 + r;
        float hv = fmaxf(h[mf][nf][reg], 0.f);
        int mt = m >> 4, rr = m & 15;
        int kc = k >> 5, kk = k & 31;
        int gg = (kk >> 2) & 3;
        int e = (kk & 3) + 4 * (kk >> 4);
        int slot = gg * 16 + ((rr + gg) & 15);
        swX[(((size_t)(mt * 4 + kc) * 64 + slot) << 3) + e] = (hf)hv;
      }
  __syncthreads();

#pragma unroll
  for (int kc = 0; kc < 4; ++kc) {
    hf8 a[4];
#pragma unroll
    for (int mf = 0; mf < 4; ++mf)
      a[mf] = *(const hf8*)(swX + (((size_t)((wm * 4 + mf) * 4 + kc) * 64 + lidx) << 3));
#pragma unroll
    for (int nf = 0; nf < 4; ++nf) {
      hf8 bw1 = ldfrag(w1f, kc, wn * 4 + nf, 8, lane);
#pragma unroll
      for (int mf = 0; mf < 4; ++mf) d[mf][nf] = MFMA16(a[mf], bw1, d[mf][nf]);
    }
  }

#pragma unroll
  for (int mf = 0; mf < 4; ++mf)
#pragma unroll
    for (int nf = 0; nf < 4; ++nf)
#pragma unroll
      for (int reg = 0; reg < 4; ++reg) {
        int m = wm * 64 + mf * 16 + 4 * g + reg;
        int n = wn * 64 + nf * 16 + r;
        net[(size_t)(t0 + m) * 128 + n] = (hf)d[mf][nf][reg];
      }
}

// ---------------- fc_c via MFMA, in-place over net --------------------------
__global__ __launch_bounds__(256, 4) void k_fcc(
    hf* __restrict__ net, const hf* __restrict__ wcf, const float* __restrict__ bc)
{
  __shared__ __align__(16) hf swX[16384];
  const int tid = threadIdx.x;
  const int wv = tid >> 6, lane = tid & 63;
  const int r = lane & 15, g = lane >> 4;
  const int wm = wv >> 1, wn = wv & 1;
  const int t0 = blockIdx.x * 128;

  for (int cc = tid; cc < 2048; cc += 256) {
    const int cl = cc & 63;
    const int kc = (cc >> 6) & 3;
    const int mt = cc >> 8;
    const int rr = cl & 15, gg = cl >> 4;
    const int t = t0 + mt * 16 + rr;
    const int c1 = kc * 32 + 4 * gg;
    union { hf8 h; uint2 u2[2]; } x;
    const hf* srcp = net + (size_t)t * 128 + c1;
    x.u2[0] = *(const uint2*)(srcp);
    x.u2[1] = *(const uint2*)(srcp + 16);
    *(hf8*)(swX + ((size_t)cc << 3)) = x.h;
  }
  __syncthreads();

  f32x4 d[4][4];
#pragma unroll
  for (int nf = 0; nf < 4; ++nf) {
    float bv = bc[wn * 64 + nf * 16 + r];
#pragma unroll
    for (int mf = 0; mf < 4; ++mf) d[mf][nf] = splat4(bv);
  }
#pragma unroll
  for (int kc = 0; kc < 4; ++kc) {
    hf8 a[4];
#pragma unroll
    for (int mf = 0; mf < 4; ++mf)
      a[mf] = *(const hf8*)(swX + (((size_t)((wm * 4 + mf) * 4 + kc) * 64 + lane) << 3));
#pragma unroll
    for (int nf = 0; nf < 4; ++nf) {
      hf8 b = ldfrag(wcf, kc, wn * 4 + nf, 8, lane);
#pragma unroll
      for (int mf = 0; mf < 4; ++mf) d[mf][nf] = MFMA16(a[mf], b, d[mf][nf]);
    }
  }

#pragma unroll
  for (int mf = 0; mf < 4; ++mf)
#pragma unroll
    for (int nf = 0; nf < 4; ++nf)
#pragma unroll
      for (int reg = 0; reg < 4; ++reg) {
        int m = wm * 64 + mf * 16 + 4 * g + reg;
        int n = wn * 64 + nf * 16 + r;
        net[(size_t)(t0 + m) * 128 + n] = (hf)d[mf][nf][reg];
      }
}

// ---------------- streaming gather-mean + transpose -------------------------
__global__ __launch_bounds__(256) void k_write(
    const hf* __restrict__ cbuf, const int* __restrict__ start,
    const int* __restrict__ cnt, float* __restrict__ out)
{
  __shared__ float tile[128 * 65];
  const int tid = threadIdx.x;
  const int grp = tid >> 4, q = tid & 15;
  const int g0 = blockIdx.x * 64;        // voxel base, (b<<15)|v0
  for (int vl = grp; vl < 64; vl += 16) {
    const int bv = g0 + vl;
    const int n = cnt[bv];
    const int end = start[bv], beg = end - n;
    float s[8] = {0, 0, 0, 0, 0, 0, 0, 0};
    for (int i = beg; i < end; ++i) {
      union { uint4 u; hf h[8]; } x;
      x.u = *(const uint4*)(cbuf + (size_t)i * 128 + 8 * q);
#pragma unroll
      for (int e = 0; e < 8; ++e) s[e] += (float)x.h[e];
    }
    const float inv = 1.0f / fmaxf((float)n, 1.0f);
#pragma unroll
    for (int e = 0; e < 8; ++e) tile[(8 * q + e) * 65 + vl] = s[e] * inv;
  }
  __syncthreads();
  const int b = g0 >> 15, v0 = g0 & 32767;
  for (int i = tid; i < 8192; i += 256) {
    const int c = i >> 6, vl = i & 63;
    out[(((size_t)(b * 128 + c)) << 15) + v0 + vl] = tile[c * 65 + vl];
  }
}

extern "C" void kernel_launch(void* const* d_in, const int* in_sizes, int n_in,
                              void* d_out, int out_size, void* d_ws, size_t ws_size,
                              hipStream_t stream)
{
  const float* p    = (const float*)d_in[0];
  const float* wpos = (const float*)d_in[1];
  const float* bpos = (const float*)d_in[2];
  const float* w0   = (const float*)d_in[3];
  const float* b0   = (const float*)d_in[4];
  const float* w1   = (const float*)d_in[5];
  const float* b1   = (const float*)d_in[6];
  const float* wsc  = (const float*)d_in[7];
  const float* wc   = (const float*)d_in[8];
  const float* bc   = (const float*)d_in[9];

  char* ws = (char*)d_ws;
  int* idxbuf = (int*)ws;                           // 1 MiB (voxel ids -> spos)
  hf*  net    = (hf*)(ws + (1u << 20));             // 64 MiB (sorted rows)
  hf*  fea    = (hf*)(ws + (65u << 20));            // 32 MiB
  int* cnt32  = (int*)(ws + (97u << 20));           // 512 KiB
  int* total  = (int*)(ws + (97u << 20) + 0x80000); // 4 B
  int* startb = (int*)(ws + (97u << 20) + 0x80400); // 512 KiB
  int* svox   = (int*)(ws + (97u << 20) + 0x100400);// 1 MiB
  hf*  fr     = (hf*)d_out;  // weight frags; d_out fully overwritten by k_write

  k_prep<<<216, 256, 0, stream>>>(wpos, w0, w1, wsc, wc, fr);

  k_idx<<<NPTS / 256, 256, 0, stream>>>(p, idxbuf);
  hipMemsetAsync(cnt32, 0, 0x80000 + 0x400, stream);
  k_count<<<NPTS / 256, 256, 0, stream>>>(idxbuf, cnt32);
  k_scan<<<NVOX / 512, 256, 0, stream>>>(cnt32, startb, total);
  k_fill<<<NPTS / 256, 256, 0, stream>>>(idxbuf, startb, svox);

  k_fused0<<<NPTS / 64, 256, 0, stream>>>(p, fr, bpos,
      fr + OFF_W0, fr + OFF_W1, fr + OFF_WSC, b0, b1, idxbuf, net);

  for (int i = 1; i < 5; ++i) {
    k_pool<<<(NVOX * 16) / 256, 256, 0, stream>>>(net, startb, cnt32, fea);
    k_res<<<NPTS / 128, 256, 0, stream>>>(net, fea, svox,
        fr + OFF_W0 + (size_t)i * 32768, fr + OFF_W1 + (size_t)i * 16384,
        fr + OFF_WSC + (size_t)i * 32768, b0 + i * 128, b1 + i * 128);
  }

  k_fcc<<<NPTS / 128, 256, 0, stream>>>(net, fr + OFF_WC, bc);
  k_write<<<NVOX / 64, 256, 0, stream>>>(net, startb, cnt32, (float*)d_out);
}

// Round 6
// 636.075 us; speedup vs baseline: 1.3832x; 1.0340x over previous
//
#include <hip/hip_runtime.h>

typedef _Float16 hf;
typedef _Float16 hf8 __attribute__((ext_vector_type(8)));
typedef float f32x4 __attribute__((ext_vector_type(4)));

static constexpr int BATCH = 4;
static constexpr int TPTS  = 65536;
static constexpr int NPTS  = BATCH * TPTS;   // 262144
static constexpr int R3    = 32768;
static constexpr int NVOX  = BATCH * R3;     // 131072

// fragment-linear f16 weight buffers (units of hf) inside d_out scratch.
static constexpr int OFF_WPOS = 0;         // K=64(pad 60), N=256: 2048 chunks
static constexpr int OFF_W0   = 16384;     // 5 x (K=256,N=128)
static constexpr int OFF_W1   = 180224;    // 5 x (K=128,N=128)
static constexpr int OFF_WSC  = 262144;    // 5 x (K=256,N=128)
static constexpr int OFF_WC   = 425984;    // K=128,N=128
static constexpr int NCHUNKS  = 55296;

__device__ constexpr int kpat(int g, int j) { return (j & 3) + 4 * g + 16 * (j >> 2); }

#define MFMA16(a, b, c) __builtin_amdgcn_mfma_f32_16x16x32_f16((a), (b), (c), 0, 0, 0)

__device__ inline hf8 relu8(hf8 a) {
#pragma unroll
  for (int i = 0; i < 8; ++i) a[i] = (a[i] > (hf)0) ? a[i] : (hf)0;
  return a;
}
__device__ inline f32x4 splat4(float v) {
  f32x4 r; r[0] = v; r[1] = v; r[2] = v; r[3] = v; return r;
}
__device__ inline hf8 ldfrag(const hf* __restrict__ base, int kc, int nt, int NT, int lane) {
  return *(const hf8*)(base + (((size_t)(kc * NT + nt) * 64 + lane) << 3));
}

// ---------------- weight fragment prep --------------------------------------
__global__ __launch_bounds__(256) void k_prep(
    const float* __restrict__ wpos, const float* __restrict__ w0,
    const float* __restrict__ w1,  const float* __restrict__ wsc,
    const float* __restrict__ wc,  hf* __restrict__ fr)
{
  const int cid = blockIdx.x * 256 + threadIdx.x;
  if (cid >= NCHUNKS) return;
  const float* src; hf* dst; int NT, N, kmax, loc;
  if (cid < 2048) {
    src = wpos; dst = fr + OFF_WPOS; NT = 16; N = 256; kmax = 60; loc = cid;
  } else if (cid < 22528) {
    int l5 = cid - 2048; int i = l5 >> 12; loc = l5 & 4095;
    src = w0 + (size_t)i * 32768; dst = fr + OFF_W0 + (size_t)i * 32768;
    NT = 8; N = 128; kmax = 256;
  } else if (cid < 32768) {
    int l5 = cid - 22528; int i = l5 >> 11; loc = l5 & 2047;
    src = w1 + (size_t)i * 16384; dst = fr + OFF_W1 + (size_t)i * 16384;
    NT = 8; N = 128; kmax = 128;
  } else if (cid < 53248) {
    int l5 = cid - 32768; int i = l5 >> 12; loc = l5 & 4095;
    src = wsc + (size_t)i * 32768; dst = fr + OFF_WSC + (size_t)i * 32768;
    NT = 8; N = 128; kmax = 256;
  } else {
    loc = cid - 53248; src = wc; dst = fr + OFF_WC; NT = 8; N = 128; kmax = 128;
  }
  const int lane = loc & 63;
  const int rest = loc >> 6;
  const int nt = rest % NT, kc = rest / NT;
  const int g = lane >> 4;
  const int n = nt * 16 + (lane & 15);
  union { hf8 h; hf f[8]; } o;
#pragma unroll
  for (int j = 0; j < 8; ++j) {
    int k = kc * 32 + kpat(g, j);
    o.f[j] = (k < kmax) ? (hf)src[(size_t)k * N + n] : (hf)0;
  }
  *(hf8*)(dst + ((size_t)loc << 3)) = o.h;
}

// ---------------- voxel index + count (fused) --------------------------------
__global__ __launch_bounds__(256) void k_idxcnt(
    const float* __restrict__ p, int* __restrict__ idxbuf, int* __restrict__ cnt)
{
  const int t = blockIdx.x * 256 + threadIdx.x;
  const float px = p[(size_t)t * 3 + 0];
  const float py = p[(size_t)t * 3 + 1];
  const float pz = p[(size_t)t * 3 + 2];
  float nx = fminf(fmaxf(px / 1.101f + 0.5f, 0.0f), 0.999f);
  float ny = fminf(fmaxf(py / 1.101f + 0.5f, 0.0f), 0.999f);
  float nz = fminf(fmaxf(pz / 1.101f + 0.5f, 0.0f), 0.999f);
  const int iv = (int)(nx * 32.f) + 32 * (int)(ny * 32.f) + 1024 * (int)(nz * 32.f);
  idxbuf[t] = iv;
  atomicAdd(&cnt[((t >> 16) << 15) | iv], 1);
}

__global__ __launch_bounds__(256) void k_scan(
    const int* __restrict__ cnt, int* __restrict__ start, int* __restrict__ total)
{
  __shared__ int s[256];
  __shared__ int base_s;
  const int tid = threadIdx.x;
  const int v0 = blockIdx.x * 512;
  const int a = cnt[v0 + 2 * tid], b = cnt[v0 + 2 * tid + 1];
  const int sum = a + b;
  s[tid] = sum;
  __syncthreads();
  for (int off = 1; off < 256; off <<= 1) {
    int x = (tid >= off) ? s[tid - off] : 0;
    __syncthreads();
    s[tid] += x;
    __syncthreads();
  }
  if (tid == 255) base_s = atomicAdd(total, s[255]);
  __syncthreads();
  const int excl = base_s + s[tid] - sum;
  start[v0 + 2 * tid]     = excl;
  start[v0 + 2 * tid + 1] = excl + a;
}

// fill: advance start[bv] to END; record sorted slot (spos, in-place over
// idxbuf) and voxel per sorted slot (svox).
__global__ __launch_bounds__(256) void k_fill(
    int* __restrict__ idxbuf, int* __restrict__ start, int* __restrict__ svox)
{
  const int t = blockIdx.x * 256 + threadIdx.x;
  const int bv = ((t >> 16) << 15) | idxbuf[t];
  const int pos = atomicAdd(&start[bv], 1);
  svox[pos] = bv;
  idxbuf[t] = pos;     // idxbuf becomes spos
}

// -------- fused: pos-enc + fc_pos (60->256) + ResnetBlock 0 (64 pts) --------
// Pos-enc computed cooperatively ONCE into frag-linear LDS (low 8KB of swX,
// dead after fc_pos), instead of 4x redundantly per wave in registers.
__global__ __launch_bounds__(256, 4) void k_fused0(
    const float* __restrict__ p, const hf* __restrict__ fr,
    const float* __restrict__ bpos,
    const hf* __restrict__ w0f, const hf* __restrict__ w1f,
    const hf* __restrict__ wscf,
    const float* __restrict__ b0, const float* __restrict__ b1,
    const int* __restrict__ spos, hf* __restrict__ net)
{
  __shared__ __align__(16) hf swX[16384];   // 32 KB: enc (8KB) -> X frags; H aliases
  __shared__ int sp[64];
  const int tid = threadIdx.x;
  const int wv = tid >> 6, lane = tid & 63;
  const int r = lane & 15, g = lane >> 4;
  const int t0 = blockIdx.x * 64;

  if (tid < 64) sp[tid] = spos[t0 + tid];

  // Phase A: cooperative pos-enc. Task tau = (pt, angle a), a = fi*3+comp,
  // 64 pts x 30 angles = 1920 tasks; each yields sin (k=6fi+comp) and
  // cos (k=6fi+comp+3). Pad slots k=60..63 zeroed (avoid NaN via 0-weight).
  if (tid < 64) {
    const int mt = tid >> 4, rr = tid & 15;
    *(unsigned long long*)(swX + (((mt * 2 + 1) * 64 + 48 + rr) << 3) + 4) = 0ull;
  }
#pragma unroll
  for (int i = 0; i < 8; ++i) {
    const int tau = tid + i * 256;
    if (tau >= 1920) break;
    const int pt = (int)(((unsigned)tau * 34953u) >> 20);   // tau/30
    const int a  = tau - pt * 30;
    const int fi = (a * 11) >> 5;                           // a/3
    const int comp = a - 3 * fi;
    const float pc = p[(size_t)(t0 + pt) * 3 + comp];
    const float ang = (float)(1 << fi) * 3.14159274101257324f * pc;
    const float sv = __sinf(ang), cv = __cosf(ang);
    const int mt = pt >> 4, rr = pt & 15;
    const int ks = 6 * fi + comp;
    {
      const int kc = ks >> 5, kk = ks & 31, gg = (kk >> 2) & 3;
      const int e = (kk & 3) + 4 * (kk >> 4);
      swX[(((mt * 2 + kc) * 64 + gg * 16 + rr) << 3) + e] = (hf)sv;
    }
    {
      const int kco = ks + 3;
      const int kc = kco >> 5, kk = kco & 31, gg = (kk >> 2) & 3;
      const int e = (kk & 3) + 4 * (kk >> 4);
      swX[(((mt * 2 + kc) * 64 + gg * 16 + rr) << 3) + e] = (hf)cv;
    }
  }
  __syncthreads();

  // fc_pos via MFMA, A-fragments from LDS
  f32x4 acc[4][4];
#pragma unroll
  for (int nf = 0; nf < 4; ++nf) {
    float bv = bpos[wv * 64 + nf * 16 + r];
#pragma unroll
    for (int mf = 0; mf < 4; ++mf) acc[mf][nf] = splat4(bv);
  }
#pragma unroll
  for (int kc = 0; kc < 2; ++kc) {
    hf8 a[4];
#pragma unroll
    for (int mf = 0; mf < 4; ++mf)
      a[mf] = *(const hf8*)(swX + (((mf * 2 + kc) * 64 + lane) << 3));
#pragma unroll
    for (int nf = 0; nf < 4; ++nf) {
      hf8 b = ldfrag(fr + OFF_WPOS, kc, wv * 4 + nf, 16, lane);
#pragma unroll
      for (int mf = 0; mf < 4; ++mf) acc[mf][nf] = MFMA16(a[mf], b, acc[mf][nf]);
    }
  }
  __syncthreads();   // enc region dead; X-store below overwrites it

  // X -> frag-linear LDS, swizzled slot
#pragma unroll
  for (int mf = 0; mf < 4; ++mf)
#pragma unroll
    for (int nf = 0; nf < 4; ++nf)
#pragma unroll
      for (int reg = 0; reg < 4; ++reg) {
        int rr = 4 * g + reg;
        int c  = wv * 64 + nf * 16 + r;
        int kc = c >> 5;
        int kk = c & 31;
        int gg = (kk >> 2) & 3;
        int e  = (kk & 3) + 4 * (kk >> 4);
        int slot = gg * 16 + ((rr + gg) & 15);
        swX[(((size_t)(mf * 8 + kc) * 64 + slot) << 3) + e] = (hf)acc[mf][nf][reg];
      }
  __syncthreads();

  const int wm = wv >> 1, wn = wv & 1;
  const int lidx = g * 16 + ((r + g) & 15);

  f32x4 h[2][4], d[2][4];
#pragma unroll
  for (int nf = 0; nf < 4; ++nf) {
    const int n = wn * 64 + nf * 16 + r;
    const float bh = b0[n], bd = b1[n];
#pragma unroll
    for (int mf = 0; mf < 2; ++mf) { h[mf][nf] = splat4(bh); d[mf][nf] = splat4(bd); }
  }
#pragma unroll 2
  for (int kc = 0; kc < 8; ++kc) {
    hf8 a[2], ar[2];
#pragma unroll
    for (int mf = 0; mf < 2; ++mf) {
      a[mf] = *(const hf8*)(swX + (((size_t)((wm * 2 + mf) * 8 + kc) * 64 + lidx) << 3));
      ar[mf] = relu8(a[mf]);
    }
#pragma unroll
    for (int nf = 0; nf < 4; ++nf) {
      hf8 bw0 = ldfrag(w0f, kc, wn * 4 + nf, 8, lane);
      hf8 bws = ldfrag(wscf, kc, wn * 4 + nf, 8, lane);
#pragma unroll
      for (int mf = 0; mf < 2; ++mf) {
        h[mf][nf] = MFMA16(ar[mf], bw0, h[mf][nf]);
        d[mf][nf] = MFMA16(a[mf],  bws, d[mf][nf]);
      }
    }
  }
  __syncthreads();

#pragma unroll
  for (int mf = 0; mf < 2; ++mf)
#pragma unroll
    for (int nf = 0; nf < 4; ++nf)
#pragma unroll
      for (int reg = 0; reg < 4; ++reg) {
        int m = wm * 32 + mf * 16 + 4 * g + reg;
        int k = wn * 64 + nf * 16 + r;
        float hv = fmaxf(h[mf][nf][reg], 0.f);
        int mt = m >> 4, rr = m & 15;
        int kc = k >> 5, kk = k & 31;
        int gg = (kk >> 2) & 3;
        int e = (kk & 3) + 4 * (kk >> 4);
        int slot = gg * 16 + ((rr + gg) & 15);
        swX[(((size_t)(mt * 4 + kc) * 64 + slot) << 3) + e] = (hf)hv;
      }
  __syncthreads();

#pragma unroll
  for (int kc = 0; kc < 4; ++kc) {
    hf8 a[2];
#pragma unroll
    for (int mf = 0; mf < 2; ++mf)
      a[mf] = *(const hf8*)(swX + (((size_t)((wm * 2 + mf) * 4 + kc) * 64 + lidx) << 3));
#pragma unroll
    for (int nf = 0; nf < 4; ++nf) {
      hf8 bw1 = ldfrag(w1f, kc, wn * 4 + nf, 8, lane);
#pragma unroll
      for (int mf = 0; mf < 2; ++mf) d[mf][nf] = MFMA16(a[mf], bw1, d[mf][nf]);
    }
  }

#pragma unroll
  for (int mf = 0; mf < 2; ++mf)
#pragma unroll
    for (int nf = 0; nf < 4; ++nf)
#pragma unroll
      for (int reg = 0; reg < 4; ++reg) {
        int m = wm * 32 + mf * 16 + 4 * g + reg;
        int n = wn * 64 + nf * 16 + r;
        net[(size_t)sp[m] * 128 + n] = (hf)d[mf][nf][reg];
      }
}

// ---------------- pool: streaming gather-max per voxel (16 lanes) -----------
__global__ __launch_bounds__(256) void k_pool(
    const hf* __restrict__ net, const int* __restrict__ start,
    const int* __restrict__ cnt, hf* __restrict__ fea)
{
  const int gid = blockIdx.x * 256 + threadIdx.x;
  const int bv = gid >> 4;
  const int q = gid & 15;
  const int n = cnt[bv];
  if (n == 0) return;
  const int end = start[bv], beg = end - n;
  float m[8];
#pragma unroll
  for (int e = 0; e < 8; ++e) m[e] = -1e30f;
  for (int i = beg; i < end; ++i) {
    union { uint4 u; hf h[8]; } x;
    x.u = *(const uint4*)(net + (size_t)i * 128 + 8 * q);
#pragma unroll
    for (int e = 0; e < 8; ++e) m[e] = fmaxf(m[e], (float)x.h[e]);
  }
  union { uint4 u; hf h[8]; } o;
#pragma unroll
  for (int e = 0; e < 8; ++e) o.h[e] = (hf)m[e];
  *(uint4*)(fea + ((size_t)bv << 7) + 8 * q) = o.u;
}

// ---- ResnetBlockFC for 128 sorted points via MFMA (64KB LDS) ---------------
__global__ __launch_bounds__(256, 2) void k_res(
    hf* __restrict__ net, const hf* __restrict__ fea,
    const int* __restrict__ svox,
    const hf* __restrict__ w0f, const hf* __restrict__ w1f,
    const hf* __restrict__ wscf,
    const float* __restrict__ b0, const float* __restrict__ b1)
{
  __shared__ __align__(16) hf swX[32768];   // 64 KB: X frags; H (32KB) aliases
  const int tid = threadIdx.x;
  const int wv = tid >> 6, lane = tid & 63;
  const int r = lane & 15, g = lane >> 4;
  const int wm = wv >> 1, wn = wv & 1;
  const int t0 = blockIdx.x * 128;
  const int lidx = g * 16 + ((r + g) & 15);

  for (int cc = tid; cc < 4096; cc += 256) {
    const int cl = cc & 63;
    const int kc = (cc >> 6) & 7;
    const int mt = cc >> 9;
    const int rr = cl & 15, gg = cl >> 4;
    const int t = t0 + mt * 16 + rr;
    const int c1 = kc * 32 + 4 * gg;
    union { hf8 h; uint2 u2[2]; } x;
    const hf* srcp;
    if (kc < 4) {
      srcp = net + (size_t)t * 128 + c1;
    } else {
      srcp = fea + (((size_t)svox[t]) << 7) + (c1 - 128);
    }
    x.u2[0] = *(const uint2*)(srcp);
    x.u2[1] = *(const uint2*)(srcp + 16);
    const int slot = gg * 16 + ((rr + gg) & 15);
    *(hf8*)(swX + (((size_t)((cc & ~63) + slot)) << 3)) = x.h;
  }
  __syncthreads();

  f32x4 h[4][4], d[4][4];
#pragma unroll
  for (int nf = 0; nf < 4; ++nf) {
    const int n = wn * 64 + nf * 16 + r;
    const float bh = b0[n], bd = b1[n];
#pragma unroll
    for (int mf = 0; mf < 4; ++mf) { h[mf][nf] = splat4(bh); d[mf][nf] = splat4(bd); }
  }
#pragma unroll 2
  for (int kc = 0; kc < 8; ++kc) {
    hf8 a[4], ar[4];
#pragma unroll
    for (int mf = 0; mf < 4; ++mf) {
      a[mf] = *(const hf8*)(swX + (((size_t)((wm * 4 + mf) * 8 + kc) * 64 + lidx) << 3));
      ar[mf] = relu8(a[mf]);
    }
#pragma unroll
    for (int nf = 0; nf < 4; ++nf) {
      hf8 bw0 = ldfrag(w0f, kc, wn * 4 + nf, 8, lane);
      hf8 bws = ldfrag(wscf, kc, wn * 4 + nf, 8, lane);
#pragma unroll
      for (int mf = 0; mf < 4; ++mf) {
        h[mf][nf] = MFMA16(ar[mf], bw0, h[mf][nf]);
        d[mf][nf] = MFMA16(a[mf],  bws, d[mf][nf]);
      }
    }
  }
  __syncthreads();

#pragma unroll
  for (int mf = 0; mf < 4; ++mf)
#pragma unroll
    for (int nf = 0; nf < 4; ++nf)
#pragma unroll
      for (int reg = 0; reg < 4; ++reg) {
        int m = wm * 64 + mf * 16 + 4 * g + reg;
        int k = wn * 64 + nf * 16 + r;
        float hv = fmaxf(h[mf][nf][reg], 0.f);
        int mt = m >> 4, rr = m & 15;
        int kc = k >> 5, kk = k & 31;
        int gg = (kk >> 2) & 3;
        int e = (kk & 3) + 4 * (kk >> 4);
        int slot = gg * 16 + ((rr + gg) & 15);
        swX[(((size_t)(mt * 4 + kc) * 64 + slot) << 3) + e] = (hf)hv;
      }
  __syncthreads();

#pragma unroll
  for (int kc = 0; kc < 4; ++kc) {
    hf8 a[4];
#pragma unroll
    for (int mf = 0; mf < 4; ++mf)
      a[mf] = *(const hf8*)(swX + (((size_t)((wm * 4 + mf) * 4 + kc) * 64 + lidx) << 3));
#pragma unroll
    for (int nf = 0; nf < 4; ++nf) {
      hf8 bw1 = ldfrag(w1f, kc, wn * 4 + nf, 8, lane);
#pragma unroll
      for (int mf = 0; mf < 4; ++mf) d[mf][nf] = MFMA16(a[mf], bw1, d[mf][nf]);
    }
  }

#pragma unroll
  for (int mf = 0; mf < 4; ++mf)
#pragma unroll
    for (int nf = 0; nf < 4; ++nf)
#pragma unroll
      for (int reg = 0; reg < 4; ++reg) {
        int m = wm * 64 + mf * 16 + 4 * g + reg;
        int n = wn * 64 + nf * 16 + r;
        net[(size_t)(t0 + m) * 128 + n] = (hf)d[mf][nf][reg];
      }
}

// ---------------- fc_c via MFMA, in-place over net --------------------------
__global__ __launch_bounds__(256, 4) void k_fcc(
    hf* __restrict__ net, const hf* __restrict__ wcf, const float* __restrict__ bc)
{
  __shared__ __align__(16) hf swX[16384];
  const int tid = threadIdx.x;
  const int wv = tid >> 6, lane = tid & 63;
  const int r = lane & 15, g = lane >> 4;
  const int wm = wv >> 1, wn = wv & 1;
  const int t0 = blockIdx.x * 128;

  for (int cc = tid; cc < 2048; cc += 256) {
    const int cl = cc & 63;
    const int kc = (cc >> 6) & 3;
    const int mt = cc >> 8;
    const int rr = cl & 15, gg = cl >> 4;
    const int t = t0 + mt * 16 + rr;
    const int c1 = kc * 32 + 4 * gg;
    union { hf8 h; uint2 u2[2]; } x;
    const hf* srcp = net + (size_t)t * 128 + c1;
    x.u2[0] = *(const uint2*)(srcp);
    x.u2[1] = *(const uint2*)(srcp + 16);
    *(hf8*)(swX + ((size_t)cc << 3)) = x.h;
  }
  __syncthreads();

  f32x4 d[4][4];
#pragma unroll
  for (int nf = 0; nf < 4; ++nf) {
    float bv = bc[wn * 64 + nf * 16 + r];
#pragma unroll
    for (int mf = 0; mf < 4; ++mf) d[mf][nf] = splat4(bv);
  }
#pragma unroll
  for (int kc = 0; kc < 4; ++kc) {
    hf8 a[4];
#pragma unroll
    for (int mf = 0; mf < 4; ++mf)
      a[mf] = *(const hf8*)(swX + (((size_t)((wm * 4 + mf) * 4 + kc) * 64 + lane) << 3));
#pragma unroll
    for (int nf = 0; nf < 4; ++nf) {
      hf8 b = ldfrag(wcf, kc, wn * 4 + nf, 8, lane);
#pragma unroll
      for (int mf = 0; mf < 4; ++mf) d[mf][nf] = MFMA16(a[mf], b, d[mf][nf]);
    }
  }

#pragma unroll
  for (int mf = 0; mf < 4; ++mf)
#pragma unroll
    for (int nf = 0; nf < 4; ++nf)
#pragma unroll
      for (int reg = 0; reg < 4; ++reg) {
        int m = wm * 64 + mf * 16 + 4 * g + reg;
        int n = wn * 64 + nf * 16 + r;
        net[(size_t)(t0 + m) * 128 + n] = (hf)d[mf][nf][reg];
      }
}

// ---------------- streaming gather-mean + transpose -------------------------
__global__ __launch_bounds__(256) void k_write(
    const hf* __restrict__ cbuf, const int* __restrict__ start,
    const int* __restrict__ cnt, float* __restrict__ out)
{
  __shared__ float tile[128 * 65];
  const int tid = threadIdx.x;
  const int grp = tid >> 4, q = tid & 15;
  const int g0 = blockIdx.x * 64;        // voxel base, (b<<15)|v0
  for (int vl = grp; vl < 64; vl += 16) {
    const int bv = g0 + vl;
    const int n = cnt[bv];
    const int end = start[bv], beg = end - n;
    float s[8] = {0, 0, 0, 0, 0, 0, 0, 0};
    for (int i = beg; i < end; ++i) {
      union { uint4 u; hf h[8]; } x;
      x.u = *(const uint4*)(cbuf + (size_t)i * 128 + 8 * q);
#pragma unroll
      for (int e = 0; e < 8; ++e) s[e] += (float)x.h[e];
    }
    const float inv = 1.0f / fmaxf((float)n, 1.0f);
#pragma unroll
    for (int e = 0; e < 8; ++e) tile[(8 * q + e) * 65 + vl] = s[e] * inv;
  }
  __syncthreads();
  const int b = g0 >> 15, v0 = g0 & 32767;
  for (int i = tid; i < 8192; i += 256) {
    const int c = i >> 6, vl = i & 63;
    out[(((size_t)(b * 128 + c)) << 15) + v0 + vl] = tile[c * 65 + vl];
  }
}

extern "C" void kernel_launch(void* const* d_in, const int* in_sizes, int n_in,
                              void* d_out, int out_size, void* d_ws, size_t ws_size,
                              hipStream_t stream)
{
  const float* p    = (const float*)d_in[0];
  const float* wpos = (const float*)d_in[1];
  const float* bpos = (const float*)d_in[2];
  const float* w0   = (const float*)d_in[3];
  const float* b0   = (const float*)d_in[4];
  const float* w1   = (const float*)d_in[5];
  const float* b1   = (const float*)d_in[6];
  const float* wsc  = (const float*)d_in[7];
  const float* wc   = (const float*)d_in[8];
  const float* bc   = (const float*)d_in[9];

  char* ws = (char*)d_ws;
  int* idxbuf = (int*)ws;                           // 1 MiB (voxel ids -> spos)
  hf*  net    = (hf*)(ws + (1u << 20));             // 64 MiB (sorted rows)
  hf*  fea    = (hf*)(ws + (65u << 20));            // 32 MiB
  int* cnt32  = (int*)(ws + (97u << 20));           // 512 KiB
  int* total  = (int*)(ws + (97u << 20) + 0x80000); // 4 B
  int* startb = (int*)(ws + (97u << 20) + 0x80400); // 512 KiB
  int* svox   = (int*)(ws + (97u << 20) + 0x100400);// 1 MiB
  hf*  fr     = (hf*)d_out;  // weight frags; d_out fully overwritten by k_write

  k_prep<<<216, 256, 0, stream>>>(wpos, w0, w1, wsc, wc, fr);

  hipMemsetAsync(cnt32, 0, 0x80000 + 0x400, stream);
  k_idxcnt<<<NPTS / 256, 256, 0, stream>>>(p, idxbuf, cnt32);
  k_scan<<<NVOX / 512, 256, 0, stream>>>(cnt32, startb, total);
  k_fill<<<NPTS / 256, 256, 0, stream>>>(idxbuf, startb, svox);

  k_fused0<<<NPTS / 64, 256, 0, stream>>>(p, fr, bpos,
      fr + OFF_W0, fr + OFF_W1, fr + OFF_WSC, b0, b1, idxbuf, net);

  for (int i = 1; i < 5; ++i) {
    k_pool<<<(NVOX * 16) / 256, 256, 0, stream>>>(net, startb, cnt32, fea);
    k_res<<<NPTS / 128, 256, 0, stream>>>(net, fea, svox,
        fr + OFF_W0 + (size_t)i * 32768, fr + OFF_W1 + (size_t)i * 16384,
        fr + OFF_WSC + (size_t)i * 32768, b0 + i * 128, b1 + i * 128);
  }

  k_fcc<<<NPTS / 128, 256, 0, stream>>>(net, fr + OFF_WC, bc);
  k_write<<<NVOX / 64, 256, 0, stream>>>(net, startb, cnt32, (float*)d_out);
}